// Round 1
// baseline (356.866 us; speedup 1.0000x reference)
//
#include <hip/hip_runtime.h>
#include <math.h>

#define N_NODES 200000
#define N_VAR   112000
#define N_EDGES 3200000
#define NB_SCAN 782           // ceil(200000/256)
#define CAP     64            // padded row capacity (P(deg>=64)~1e-24)

// ---- two-phase binning scatter params ----
#define NPART    32           // dst-range buckets
#define PSZ      6250         // nodes per bucket (32*6250 = 200000)
#define BCAP     104448       // per-bucket capacity (mean 100000, ~14 sigma slack)
#define BIN_CHUNK 4096        // edges per k_bin block
#define NB_BIN   782          // ceil(3.2e6/4096)
#define BPP      128          // blocks per bucket in k_scat2

typedef int v4i __attribute__((ext_vector_type(4)));

// ---------- setup: zero cnt + bcnt (block 0) + fold Wc = W2@Wfc, bc ----------
__global__ void __launch_bounds__(256) k_setup(const float* __restrict__ W2,
                                               const float* __restrict__ b2,
                                               const float* __restrict__ Wfc,
                                               const float* __restrict__ bfc,
                                               float* __restrict__ Wc,
                                               float* __restrict__ bc,
                                               int* __restrict__ cnt,
                                               int* __restrict__ bcnt) {
    int b = blockIdx.x;
    int i = b * 256 + threadIdx.x;
    if (i < N_NODES) cnt[i] = 0;
    if (i < NPART) bcnt[i] = 0;
    if (b < 16) {
        int e = b * 256 + threadIdx.x;     // 4096 entries
        int j = e >> 6, l = e & 63;
        double acc = 0.0;
        for (int m = 0; m < 64; ++m)
            acc += (double)W2[j * 64 + m] * (double)Wfc[m * 64 + l];
        Wc[e] = (float)acc;
    } else if (b == 16 && threadIdx.x < 64) {
        int l = threadIdx.x;
        double acc = (double)bfc[l];
        for (int m = 0; m < 64; ++m)
            acc += (double)b2[m] * (double)Wfc[m * 64 + l];
        bc[l] = (float)acc;
    }
}

// ---------- phase A: bin edges by dst range, packed (dst_local<<18 | src) ----------
// Single pass over edges. LDS staging -> coalesced bucket-segment writes.
__global__ void __launch_bounds__(256) k_bin(const int* __restrict__ src,
                                             const int* __restrict__ dst,
                                             int* __restrict__ bins,
                                             int* __restrict__ bcnt) {
    __shared__ int hist[NPART];
    __shared__ int seg[NPART];         // exclusive prefix of hist
    __shared__ int gb[NPART];          // global base per bucket
    __shared__ int cur[NPART];
    __shared__ int stg[BIN_CHUNK];
    int tid = threadIdx.x;
    if (tid < NPART) hist[tid] = 0;
    __syncthreads();

    int base = blockIdx.x * BIN_CHUNK;
    int pk[4][4];
    int bk[4][4];
    bool val[4];
    #pragma unroll
    for (int i = 0; i < 4; ++i) {
        int e4 = base + (i * 256 + tid) * 4;
        val[i] = (e4 < N_EDGES);       // N_EDGES % 4 == 0 -> full quad if valid
        if (val[i]) {
            v4i d = __builtin_nontemporal_load((const v4i*)(dst + e4));
            v4i s = __builtin_nontemporal_load((const v4i*)(src + e4));
            int dd[4] = {d.x, d.y, d.z, d.w};
            int ss[4] = {s.x, s.y, s.z, s.w};
            #pragma unroll
            for (int q = 0; q < 4; ++q) {
                int bb = dd[q] / PSZ;                  // const div -> mul/shift
                int dl = dd[q] - bb * PSZ;             // < 6250 (13 bits)
                pk[i][q] = (dl << 18) | ss[q];         // src < 2^18
                bk[i][q] = bb;
                atomicAdd(&hist[bb], 1);
            }
        }
    }
    __syncthreads();

    if (tid == 0) {
        int run = 0;
        #pragma unroll
        for (int bb = 0; bb < NPART; ++bb) { seg[bb] = run; run += hist[bb]; }
    }
    if (tid < NPART) gb[tid] = atomicAdd(&bcnt[tid], hist[tid]);
    __syncthreads();
    if (tid < NPART) cur[tid] = seg[tid];
    __syncthreads();

    #pragma unroll
    for (int i = 0; i < 4; ++i) {
        if (val[i]) {
            #pragma unroll
            for (int q = 0; q < 4; ++q) {
                int p = atomicAdd(&cur[bk[i][q]], 1);
                stg[p] = pk[i][q];
            }
        }
    }
    __syncthreads();

    // coalesced copy-out: per bucket, a contiguous run into the bucket's segment
    for (int bb = 0; bb < NPART; ++bb) {
        int h = hist[bb], s0 = seg[bb];
        long gpos = (long)bb * BCAP + gb[bb];
        long lim  = (long)(bb + 1) * BCAP;
        for (int t = tid; t < h; t += 256)
            if (gpos + t < lim) bins[gpos + t] = stg[s0 + t];
    }
}

// ---------- phase B: per-bucket scatter into padded adjacency ----------
// Bucket buf region = 1.6 MB << 4 MB XCD L2. XCD = blockIdx&7 pins each
// bucket to one XCD; 4 sequential phases/XCD keep the hot region L2-resident
// so the 4B scattered writes combine into full lines before eviction.
__global__ void __launch_bounds__(256) k_scat2(const int* __restrict__ bins,
                                               const int* __restrict__ bcnt,
                                               int* __restrict__ cnt,
                                               int* __restrict__ buf) {
    int bid = blockIdx.x;
    int xcd = bid & 7;
    int j = bid >> 3;
    int phase = j / BPP;               // 0..3
    int k = j - phase * BPP;           // 0..BPP-1
    int p = phase * 8 + xcd;           // bucket 0..31
    int nb = bcnt[p];
    if (nb > BCAP) nb = BCAP;
    const int* __restrict__ bp = bins + (long)p * BCAP;
    const v4i* __restrict__ bp4 = (const v4i*)bp;
    int vbase = p * PSZ;

    int nc = nb >> 2;
    for (int c = k * 256 + threadIdx.x; c < nc; c += BPP * 256) {
        v4i v = bp4[c];
        int s0 = v.x & 0x3FFFF, d0 = vbase + (v.x >> 18);
        int s1 = v.y & 0x3FFFF, d1 = vbase + (v.y >> 18);
        int s2 = v.z & 0x3FFFF, d2 = vbase + (v.z >> 18);
        int s3 = v.w & 0x3FFFF, d3 = vbase + (v.w >> 18);
        int p0 = atomicAdd(&cnt[d0], 1); if (p0 < CAP) buf[d0 * CAP + p0] = s0;
        int p1 = atomicAdd(&cnt[d1], 1); if (p1 < CAP) buf[d1 * CAP + p1] = s1;
        int p2 = atomicAdd(&cnt[d2], 1); if (p2 < CAP) buf[d2 * CAP + p2] = s2;
        int p3 = atomicAdd(&cnt[d3], 1); if (p3 < CAP) buf[d3 * CAP + p3] = s3;
    }
    // tail (nb % 4)
    if (k == 0 && threadIdx.x < (nb & 3)) {
        int v = bp[(nb & ~3) + threadIdx.x];
        int s = v & 0x3FFFF, d = vbase + (v >> 18);
        int p0 = atomicAdd(&cnt[d], 1);
        if (p0 < CAP) buf[d * CAP + p0] = s;
    }
}

// ---------- post: xdc[v] = (xn.x, xn.y, dv, 0)  (packed gather table, 3.2MB) ----------
__global__ void __launch_bounds__(256) k_post(const int* __restrict__ cnt,
                                              const float2* __restrict__ x2,
                                              float4* __restrict__ xdc) {
    int i = blockIdx.x * 256 + threadIdx.x;
    if (i >= N_NODES) return;
    float dv = rsqrtf((float)cnt[i] + 1.0f);
    float2 xv = x2[i];
    xdc[i] = make_float4(xv.x * dv, xv.y * dv, dv, 0.0f);
}

// ---------- layer 1: zn[v] = (i0, i1, dv, 0) ----------
__global__ void __launch_bounds__(256) k_l1a(const int* __restrict__ cnt,
                                             const int* __restrict__ buf,
                                             const float4* __restrict__ xdc,
                                             float4* __restrict__ zn) {
    int v = blockIdx.x * 256 + threadIdx.x;
    if (v >= N_NODES) return;
    int c = cnt[v];
    int n = (c < CAP) ? c : CAP;
    const int* __restrict__ rowp = buf + v * CAP;
    float4 self = xdc[v];
    float dv = self.z;
    double ax = self.x, ay = self.y;
    double bx = 0.0,    by = 0.0;
    int j = 0;
    for (; j + 16 <= n; j += 16) {
        v4i r0 = *(const v4i*)(rowp + j);
        v4i r1 = *(const v4i*)(rowp + j + 4);
        v4i r2 = *(const v4i*)(rowp + j + 8);
        v4i r3 = *(const v4i*)(rowp + j + 12);
        float4 p0 = xdc[r0.x], p1 = xdc[r0.y], p2 = xdc[r0.z], p3 = xdc[r0.w];
        float4 p4 = xdc[r1.x], p5 = xdc[r1.y], p6 = xdc[r1.z], p7 = xdc[r1.w];
        float4 p8 = xdc[r2.x], p9 = xdc[r2.y], pa = xdc[r2.z], pb = xdc[r2.w];
        float4 pc = xdc[r3.x], pd = xdc[r3.y], pe = xdc[r3.z], pf = xdc[r3.w];
        ax += p0.x; ay += p0.y;  bx += p1.x; by += p1.y;
        ax += p2.x; ay += p2.y;  bx += p3.x; by += p3.y;
        ax += p4.x; ay += p4.y;  bx += p5.x; by += p5.y;
        ax += p6.x; ay += p6.y;  bx += p7.x; by += p7.y;
        ax += p8.x; ay += p8.y;  bx += p9.x; by += p9.y;
        ax += pa.x; ay += pa.y;  bx += pb.x; by += pb.y;
        ax += pc.x; ay += pc.y;  bx += pd.x; by += pd.y;
        ax += pe.x; ay += pe.y;  bx += pf.x; by += pf.y;
    }
    for (; j + 8 <= n; j += 8) {
        v4i r0 = *(const v4i*)(rowp + j);
        v4i r1 = *(const v4i*)(rowp + j + 4);
        float4 p0 = xdc[r0.x], p1 = xdc[r0.y], p2 = xdc[r0.z], p3 = xdc[r0.w];
        float4 p4 = xdc[r1.x], p5 = xdc[r1.y], p6 = xdc[r1.z], p7 = xdc[r1.w];
        ax += p0.x; ay += p0.y;  bx += p1.x; by += p1.y;
        ax += p2.x; ay += p2.y;  bx += p3.x; by += p3.y;
        ax += p4.x; ay += p4.y;  bx += p5.x; by += p5.y;
        ax += p6.x; ay += p6.y;  bx += p7.x; by += p7.y;
    }
    for (; j < n; ++j) {
        int s = rowp[j];
        float4 p = xdc[s];
        ax += p.x; ay += p.y;
    }
    zn[v] = make_float4((float)(ax + bx) * dv, (float)(ay + by) * dv, dv, 0.0f);
}

// ---------- layer 2 + folded fc, var nodes only ----------
__global__ void __launch_bounds__(256) k_l2(const int* __restrict__ cnt,
                                            const int* __restrict__ buf,
                                            const float4* __restrict__ zn,
                                            const float* __restrict__ W1,
                                            const float* __restrict__ b1,
                                            const float* __restrict__ Wc,
                                            const float* __restrict__ bc,
                                            float* __restrict__ out) {
    __shared__ float Wcs[4096];            // 16 KB
    __shared__ float A[4][64];
    int w = threadIdx.x >> 6, l = threadIdx.x & 63;
    #pragma unroll
    for (int k = 0; k < 16; ++k)
        Wcs[k * 256 + threadIdx.x] = Wc[k * 256 + threadIdx.x];
    float w1a = W1[l], w1b = W1[64 + l], bb = b1[l];
    float bcl = bc[l];
    int v0 = blockIdx.x * 16 + w;          // wave w owns v0, v0+4, v0+8, v0+12
    int cA = __builtin_amdgcn_readfirstlane(cnt[v0]);
    int cB = __builtin_amdgcn_readfirstlane(cnt[v0 + 4]);
    int cC = __builtin_amdgcn_readfirstlane(cnt[v0 + 8]);
    int cD = __builtin_amdgcn_readfirstlane(cnt[v0 + 12]);
    __syncthreads();                       // Wcs ready -- the ONLY barrier

    #pragma unroll
    for (int it = 0; it < 4; ++it) {
        int v = v0 + it * 4;
        int c = (it == 0) ? cA : (it == 1) ? cB : (it == 2) ? cC : cD;
        int n = (c < CAP) ? c : CAP;
        float dv = rsqrtf((float)c + 1.0f);
        const int* __restrict__ row = buf + v * CAP;

        float4 zs = zn[v];                 // self (broadcast)
        float hs = fmaxf(fmaf(zs.x, w1a, fmaf(zs.y, w1b, bb)), 0.0f) * zs.z;
        double acc = (double)hs;
        int j = 0;
        for (; j + 8 <= n; j += 8) {
            v4i ra = *(const v4i*)(row + j);
            v4i rb = *(const v4i*)(row + j + 4);
            int s0 = __builtin_amdgcn_readfirstlane(ra.x);
            int s1 = __builtin_amdgcn_readfirstlane(ra.y);
            int s2 = __builtin_amdgcn_readfirstlane(ra.z);
            int s3 = __builtin_amdgcn_readfirstlane(ra.w);
            int s4 = __builtin_amdgcn_readfirstlane(rb.x);
            int s5 = __builtin_amdgcn_readfirstlane(rb.y);
            int s6 = __builtin_amdgcn_readfirstlane(rb.z);
            int s7 = __builtin_amdgcn_readfirstlane(rb.w);
            float4 p0 = zn[s0], p1 = zn[s1], p2 = zn[s2], p3 = zn[s3];
            float4 p4 = zn[s4], p5 = zn[s5], p6 = zn[s6], p7 = zn[s7];
            float h0 = fmaxf(fmaf(p0.x, w1a, fmaf(p0.y, w1b, bb)), 0.0f) * p0.z;
            float h1 = fmaxf(fmaf(p1.x, w1a, fmaf(p1.y, w1b, bb)), 0.0f) * p1.z;
            float h2 = fmaxf(fmaf(p2.x, w1a, fmaf(p2.y, w1b, bb)), 0.0f) * p2.z;
            float h3 = fmaxf(fmaf(p3.x, w1a, fmaf(p3.y, w1b, bb)), 0.0f) * p3.z;
            float h4 = fmaxf(fmaf(p4.x, w1a, fmaf(p4.y, w1b, bb)), 0.0f) * p4.z;
            float h5 = fmaxf(fmaf(p5.x, w1a, fmaf(p5.y, w1b, bb)), 0.0f) * p5.z;
            float h6 = fmaxf(fmaf(p6.x, w1a, fmaf(p6.y, w1b, bb)), 0.0f) * p6.z;
            float h7 = fmaxf(fmaf(p7.x, w1a, fmaf(p7.y, w1b, bb)), 0.0f) * p7.z;
            acc += h0; acc += h1; acc += h2; acc += h3;
            acc += h4; acc += h5; acc += h6; acc += h7;
        }
        for (; j + 4 <= n; j += 4) {
            v4i ra = *(const v4i*)(row + j);
            int s0 = __builtin_amdgcn_readfirstlane(ra.x);
            int s1 = __builtin_amdgcn_readfirstlane(ra.y);
            int s2 = __builtin_amdgcn_readfirstlane(ra.z);
            int s3 = __builtin_amdgcn_readfirstlane(ra.w);
            float4 p0 = zn[s0], p1 = zn[s1], p2 = zn[s2], p3 = zn[s3];
            float h0 = fmaxf(fmaf(p0.x, w1a, fmaf(p0.y, w1b, bb)), 0.0f) * p0.z;
            float h1 = fmaxf(fmaf(p1.x, w1a, fmaf(p1.y, w1b, bb)), 0.0f) * p1.z;
            float h2 = fmaxf(fmaf(p2.x, w1a, fmaf(p2.y, w1b, bb)), 0.0f) * p2.z;
            float h3 = fmaxf(fmaf(p3.x, w1a, fmaf(p3.y, w1b, bb)), 0.0f) * p3.z;
            acc += h0; acc += h1; acc += h2; acc += h3;
        }
        for (; j < n; ++j) {
            int s = __builtin_amdgcn_readfirstlane(row[j]);
            float4 p = zn[s];
            acc += fmaxf(fmaf(p.x, w1a, fmaf(p.y, w1b, bb)), 0.0f) * p.z;
        }
        A[w][l] = (float)acc * dv;         // wave-private row, no barrier needed
        double t = 0.0;
        #pragma unroll
        for (int jj = 0; jj < 64; ++jj)
            t += (double)A[w][jj] * (double)Wcs[jj * 64 + l];
        out[v * 64 + l] = rintf(fmaxf((float)t + bcl, 0.0f));
    }
}

// ---------------- launch ----------------

extern "C" void kernel_launch(void* const* d_in, const int* in_sizes, int n_in,
                              void* d_out, int out_size, void* d_ws, size_t ws_size,
                              hipStream_t stream) {
    const float* x    = (const float*)d_in[0];
    const int*   ei   = (const int*)  d_in[1];
    const float* W1   = (const float*)d_in[2];
    const float* b1   = (const float*)d_in[3];
    const float* W2   = (const float*)d_in[4];
    const float* b2   = (const float*)d_in[5];
    const float* Wfc  = (const float*)d_in[6];
    const float* bfc  = (const float*)d_in[7];
    float* out = (float*)d_out;

    const int* src = ei;
    const int* dst = ei + N_EDGES;

    // workspace layout (bytes), 16-aligned; total 70,420,736 (unchanged)
    // bins (13.37 MB) + bcnt alias the xdc/zn/spare region [3,204,096 .. 19,204,096):
    // they are dead before k_post writes xdc (same-stream ordering).
    char* ws = (char*)d_ws;
    int*    cnt    = (int*)   (ws + 0);          //   800,000
    float4* xdc    = (float4*)(ws + 3204096);    // 3,200,000
    float4* zn     = (float4*)(ws + 6404096);    // 3,200,000
    int*    bins   = (int*)   (ws + 3204096);    // 13,369,344 (alias, dead after k_scat2)
    int*    bcnt   = (int*)   (ws + 16573440);   //       128  (alias, dead after k_scat2)
    int*    buf    = (int*)   (ws + 19204096);   // 51,200,000 padded adjacency
    float*  Wc     = (float*) (ws + 70404096);   //    16,384
    float*  bc     = (float*) (ws + 70420480);   //       256

    k_setup <<<NB_SCAN, 256, 0, stream>>>(W2, b2, Wfc, bfc, Wc, bc, cnt, bcnt);
    k_bin   <<<NB_BIN, 256, 0, stream>>>(src, dst, bins, bcnt);
    k_scat2 <<<NPART * BPP, 256, 0, stream>>>(bins, bcnt, cnt, buf);
    k_post  <<<NB_SCAN, 256, 0, stream>>>(cnt, (const float2*)x, xdc);
    k_l1a   <<<NB_SCAN, 256, 0, stream>>>(cnt, buf, xdc, zn);
    k_l2    <<<N_VAR / 16, 256, 0, stream>>>(cnt, buf, zn, W1, b1, Wc, bc, out);
}

// Round 2
// 238.187 us; speedup vs baseline: 1.4983x; 1.4983x over previous
//
#include <hip/hip_runtime.h>
#include <math.h>

#define N_NODES 200000
#define N_VAR   112000
#define N_EDGES 3200000
#define NB_SCAN 782           // ceil(200000/256)
#define CAP     64            // padded row capacity (P(deg>=64)~1e-24)

// ---- two-level counting-sort params ----
#define NFINE    512          // fine dst-range buckets
#define PSZ_F    391          // nodes per bucket (512*391 = 200192 >= 200000)
#define FCAP     7168         // per-bucket edge capacity (mean 6250, ~11.6 sigma slack)
#define BIN_CHUNK 8192        // edges per k_bin block
#define NB_BIN   391          // ceil(3.2e6/8192)

typedef int v4i __attribute__((ext_vector_type(4)));

// ---------- setup: zero bcnt + fold Wc = W2@Wfc, bc ----------
// (cnt no longer needs zeroing: k_sort writes every cnt[v] exactly once)
__global__ void __launch_bounds__(256) k_setup(const float* __restrict__ W2,
                                               const float* __restrict__ b2,
                                               const float* __restrict__ Wfc,
                                               const float* __restrict__ bfc,
                                               float* __restrict__ Wc,
                                               float* __restrict__ bc,
                                               int* __restrict__ bcnt) {
    int b = blockIdx.x;
    int i = b * 256 + threadIdx.x;
    if (i < NFINE) bcnt[i] = 0;
    if (b < 16) {
        int e = b * 256 + threadIdx.x;     // 4096 entries
        int j = e >> 6, l = e & 63;
        double acc = 0.0;
        for (int m = 0; m < 64; ++m)
            acc += (double)W2[j * 64 + m] * (double)Wfc[m * 64 + l];
        Wc[e] = (float)acc;
    } else if (b == 16 && threadIdx.x < 64) {
        int l = threadIdx.x;
        double acc = (double)bfc[l];
        for (int m = 0; m < 64; ++m)
            acc += (double)b2[m] * (double)Wfc[m * 64 + l];
        bc[l] = (float)acc;
    }
}

// ---------- phase A: bin edges into 512 dst-range buckets ----------
// Packed entry: (dst_local<<18 | src), dst_local<391 (9b), src<2^18.
// LDS compact by bucket -> coalesced segment writes (avg 16 edges = 64B/segment).
__global__ void __launch_bounds__(512) k_bin(const int* __restrict__ src,
                                             const int* __restrict__ dst,
                                             int* __restrict__ bins,
                                             int* __restrict__ bcnt) {
    __shared__ int hist[NFINE];
    __shared__ int seg[NFINE];         // exclusive prefix (stg position base)
    __shared__ int gb[NFINE];          // global base per bucket
    __shared__ int cur[NFINE];
    __shared__ int scn[NFINE];
    __shared__ int stg[BIN_CHUNK];
    __shared__ unsigned short stgb[BIN_CHUNK];
    int tid = threadIdx.x;
    hist[tid] = 0;
    __syncthreads();

    int base = blockIdx.x * BIN_CHUNK;
    int pk[4][4];
    int bk[4][4];
    bool val[4];
    #pragma unroll
    for (int i = 0; i < 4; ++i) {
        int e4 = base + (i * 512 + tid) * 4;
        val[i] = (e4 < N_EDGES);       // N_EDGES % 4 == 0 -> full quad if valid
        if (val[i]) {
            v4i d = __builtin_nontemporal_load((const v4i*)(dst + e4));
            v4i s = __builtin_nontemporal_load((const v4i*)(src + e4));
            int dd[4] = {d.x, d.y, d.z, d.w};
            int ss[4] = {s.x, s.y, s.z, s.w};
            #pragma unroll
            for (int q = 0; q < 4; ++q) {
                int bb = dd[q] / PSZ_F;                // const div -> magic mul
                int dl = dd[q] - bb * PSZ_F;           // < 391 (9 bits)
                pk[i][q] = (dl << 18) | ss[q];
                bk[i][q] = bb;
                atomicAdd(&hist[bb], 1);
            }
        }
    }
    __syncthreads();

    // inclusive Hillis-Steele scan of hist over 512 entries
    scn[tid] = hist[tid];
    __syncthreads();
    for (int d = 1; d < NFINE; d <<= 1) {
        int t = scn[tid];
        int u = (tid >= d) ? scn[tid - d] : 0;
        __syncthreads();
        scn[tid] = t + u;
        __syncthreads();
    }
    int ex = scn[tid] - hist[tid];
    seg[tid] = ex;
    cur[tid] = ex;
    gb[tid]  = atomicAdd(&bcnt[tid], hist[tid]);
    __syncthreads();
    int tot = scn[NFINE - 1];

    // compact into stg by bucket
    #pragma unroll
    for (int i = 0; i < 4; ++i) {
        if (val[i]) {
            #pragma unroll
            for (int q = 0; q < 4; ++q) {
                int p = atomicAdd(&cur[bk[i][q]], 1);
                stg[p]  = pk[i][q];
                stgb[p] = (unsigned short)bk[i][q];
            }
        }
    }
    __syncthreads();

    // coalesced copy-out: consecutive i -> mostly-consecutive global addresses
    for (int i = tid; i < tot; i += 512) {
        int bb  = stgb[i];
        int pos = gb[bb] + (i - seg[bb]);
        if (pos < FCAP)
            bins[(size_t)bb * FCAP + pos] = stg[i];
    }
}

// ---------- phase B: per-bucket counting sort -> exact cnt + coalesced buf rows ----------
// Zero global atomics. One block per bucket (~6250 edges, 391 nodes).
__global__ void __launch_bounds__(512) k_sort(const int* __restrict__ bins,
                                              const int* __restrict__ bcnt,
                                              int* __restrict__ cnt,
                                              int* __restrict__ buf) {
    __shared__ int hist[NFINE];        // 0..390 used; padded to 512 for scan
    __shared__ int scn[NFINE];
    __shared__ int off[NFINE];
    __shared__ int cur[NFINE];
    __shared__ int sorted[FCAP];       // 28.7 KB
    __shared__ unsigned short rowid[FCAP]; // 14.3 KB
    int tid = threadIdx.x;
    int b = blockIdx.x;
    int n = bcnt[b];
    if (n > FCAP) n = FCAP;
    const int* __restrict__ bp = bins + (size_t)b * FCAP;

    hist[tid] = 0;
    __syncthreads();
    for (int i = tid; i < n; i += 512)
        atomicAdd(&hist[bp[i] >> 18], 1);       // LDS histogram
    __syncthreads();

    // exact degree -> cnt (replaces all global cnt atomics)
    int v = b * PSZ_F + tid;
    if (tid < PSZ_F && v < N_NODES) cnt[v] = hist[tid];

    // inclusive scan -> exclusive offsets
    scn[tid] = hist[tid];
    __syncthreads();
    for (int d = 1; d < NFINE; d <<= 1) {
        int t = scn[tid];
        int u = (tid >= d) ? scn[tid - d] : 0;
        __syncthreads();
        scn[tid] = t + u;
        __syncthreads();
    }
    int ex = scn[tid] - hist[tid];
    off[tid] = ex;
    cur[tid] = ex;
    __syncthreads();

    // LDS reorder: dst-sorted edge list
    for (int i = tid; i < n; i += 512) {
        int pk = bp[i];                         // L2-hit (just read in pass 1)
        int dl = pk >> 18;
        int p = atomicAdd(&cur[dl], 1);
        sorted[p] = pk & 0x3FFFF;
        rowid[p]  = (unsigned short)dl;
    }
    __syncthreads();

    // monotone coalesced write-out of padded rows
    for (int i = tid; i < n; i += 512) {
        int dl = rowid[i];
        int slot = i - off[dl];
        if (slot < CAP)
            buf[(size_t)(b * PSZ_F + dl) * CAP + slot] = sorted[i];
    }
}

// ---------- post: xdc[v] = (xn.x, xn.y, dv, 0)  (packed gather table, 3.2MB) ----------
__global__ void __launch_bounds__(256) k_post(const int* __restrict__ cnt,
                                              const float2* __restrict__ x2,
                                              float4* __restrict__ xdc) {
    int i = blockIdx.x * 256 + threadIdx.x;
    if (i >= N_NODES) return;
    float dv = rsqrtf((float)cnt[i] + 1.0f);
    float2 xv = x2[i];
    xdc[i] = make_float4(xv.x * dv, xv.y * dv, dv, 0.0f);
}

// ---------- layer 1: zn[v] = (i0, i1, dv, 0) ----------
__global__ void __launch_bounds__(256) k_l1a(const int* __restrict__ cnt,
                                             const int* __restrict__ buf,
                                             const float4* __restrict__ xdc,
                                             float4* __restrict__ zn) {
    int v = blockIdx.x * 256 + threadIdx.x;
    if (v >= N_NODES) return;
    int c = cnt[v];
    int n = (c < CAP) ? c : CAP;
    const int* __restrict__ rowp = buf + v * CAP;
    float4 self = xdc[v];
    float dv = self.z;
    double ax = self.x, ay = self.y;
    double bx = 0.0,    by = 0.0;
    int j = 0;
    for (; j + 16 <= n; j += 16) {
        v4i r0 = *(const v4i*)(rowp + j);
        v4i r1 = *(const v4i*)(rowp + j + 4);
        v4i r2 = *(const v4i*)(rowp + j + 8);
        v4i r3 = *(const v4i*)(rowp + j + 12);
        float4 p0 = xdc[r0.x], p1 = xdc[r0.y], p2 = xdc[r0.z], p3 = xdc[r0.w];
        float4 p4 = xdc[r1.x], p5 = xdc[r1.y], p6 = xdc[r1.z], p7 = xdc[r1.w];
        float4 p8 = xdc[r2.x], p9 = xdc[r2.y], pa = xdc[r2.z], pb = xdc[r2.w];
        float4 pc = xdc[r3.x], pd = xdc[r3.y], pe = xdc[r3.z], pf = xdc[r3.w];
        ax += p0.x; ay += p0.y;  bx += p1.x; by += p1.y;
        ax += p2.x; ay += p2.y;  bx += p3.x; by += p3.y;
        ax += p4.x; ay += p4.y;  bx += p5.x; by += p5.y;
        ax += p6.x; ay += p6.y;  bx += p7.x; by += p7.y;
        ax += p8.x; ay += p8.y;  bx += p9.x; by += p9.y;
        ax += pa.x; ay += pa.y;  bx += pb.x; by += pb.y;
        ax += pc.x; ay += pc.y;  bx += pd.x; by += pd.y;
        ax += pe.x; ay += pe.y;  bx += pf.x; by += pf.y;
    }
    for (; j + 8 <= n; j += 8) {
        v4i r0 = *(const v4i*)(rowp + j);
        v4i r1 = *(const v4i*)(rowp + j + 4);
        float4 p0 = xdc[r0.x], p1 = xdc[r0.y], p2 = xdc[r0.z], p3 = xdc[r0.w];
        float4 p4 = xdc[r1.x], p5 = xdc[r1.y], p6 = xdc[r1.z], p7 = xdc[r1.w];
        ax += p0.x; ay += p0.y;  bx += p1.x; by += p1.y;
        ax += p2.x; ay += p2.y;  bx += p3.x; by += p3.y;
        ax += p4.x; ay += p4.y;  bx += p5.x; by += p5.y;
        ax += p6.x; ay += p6.y;  bx += p7.x; by += p7.y;
    }
    for (; j < n; ++j) {
        int s = rowp[j];
        float4 p = xdc[s];
        ax += p.x; ay += p.y;
    }
    zn[v] = make_float4((float)(ax + bx) * dv, (float)(ay + by) * dv, dv, 0.0f);
}

// ---------- layer 2 + folded fc, var nodes only ----------
__global__ void __launch_bounds__(256) k_l2(const int* __restrict__ cnt,
                                            const int* __restrict__ buf,
                                            const float4* __restrict__ zn,
                                            const float* __restrict__ W1,
                                            const float* __restrict__ b1,
                                            const float* __restrict__ Wc,
                                            const float* __restrict__ bc,
                                            float* __restrict__ out) {
    __shared__ float Wcs[4096];            // 16 KB
    __shared__ float A[4][64];
    int w = threadIdx.x >> 6, l = threadIdx.x & 63;
    #pragma unroll
    for (int k = 0; k < 16; ++k)
        Wcs[k * 256 + threadIdx.x] = Wc[k * 256 + threadIdx.x];
    float w1a = W1[l], w1b = W1[64 + l], bb = b1[l];
    float bcl = bc[l];
    int v0 = blockIdx.x * 16 + w;          // wave w owns v0, v0+4, v0+8, v0+12
    int cA = __builtin_amdgcn_readfirstlane(cnt[v0]);
    int cB = __builtin_amdgcn_readfirstlane(cnt[v0 + 4]);
    int cC = __builtin_amdgcn_readfirstlane(cnt[v0 + 8]);
    int cD = __builtin_amdgcn_readfirstlane(cnt[v0 + 12]);
    __syncthreads();                       // Wcs ready -- the ONLY barrier

    #pragma unroll
    for (int it = 0; it < 4; ++it) {
        int v = v0 + it * 4;
        int c = (it == 0) ? cA : (it == 1) ? cB : (it == 2) ? cC : cD;
        int n = (c < CAP) ? c : CAP;
        float dv = rsqrtf((float)c + 1.0f);
        const int* __restrict__ row = buf + v * CAP;

        float4 zs = zn[v];                 // self (broadcast)
        float hs = fmaxf(fmaf(zs.x, w1a, fmaf(zs.y, w1b, bb)), 0.0f) * zs.z;
        double acc = (double)hs;
        int j = 0;
        for (; j + 8 <= n; j += 8) {
            v4i ra = *(const v4i*)(row + j);
            v4i rb = *(const v4i*)(row + j + 4);
            int s0 = __builtin_amdgcn_readfirstlane(ra.x);
            int s1 = __builtin_amdgcn_readfirstlane(ra.y);
            int s2 = __builtin_amdgcn_readfirstlane(ra.z);
            int s3 = __builtin_amdgcn_readfirstlane(ra.w);
            int s4 = __builtin_amdgcn_readfirstlane(rb.x);
            int s5 = __builtin_amdgcn_readfirstlane(rb.y);
            int s6 = __builtin_amdgcn_readfirstlane(rb.z);
            int s7 = __builtin_amdgcn_readfirstlane(rb.w);
            float4 p0 = zn[s0], p1 = zn[s1], p2 = zn[s2], p3 = zn[s3];
            float4 p4 = zn[s4], p5 = zn[s5], p6 = zn[s6], p7 = zn[s7];
            float h0 = fmaxf(fmaf(p0.x, w1a, fmaf(p0.y, w1b, bb)), 0.0f) * p0.z;
            float h1 = fmaxf(fmaf(p1.x, w1a, fmaf(p1.y, w1b, bb)), 0.0f) * p1.z;
            float h2 = fmaxf(fmaf(p2.x, w1a, fmaf(p2.y, w1b, bb)), 0.0f) * p2.z;
            float h3 = fmaxf(fmaf(p3.x, w1a, fmaf(p3.y, w1b, bb)), 0.0f) * p3.z;
            float h4 = fmaxf(fmaf(p4.x, w1a, fmaf(p4.y, w1b, bb)), 0.0f) * p4.z;
            float h5 = fmaxf(fmaf(p5.x, w1a, fmaf(p5.y, w1b, bb)), 0.0f) * p5.z;
            float h6 = fmaxf(fmaf(p6.x, w1a, fmaf(p6.y, w1b, bb)), 0.0f) * p6.z;
            float h7 = fmaxf(fmaf(p7.x, w1a, fmaf(p7.y, w1b, bb)), 0.0f) * p7.z;
            acc += h0; acc += h1; acc += h2; acc += h3;
            acc += h4; acc += h5; acc += h6; acc += h7;
        }
        for (; j + 4 <= n; j += 4) {
            v4i ra = *(const v4i*)(row + j);
            int s0 = __builtin_amdgcn_readfirstlane(ra.x);
            int s1 = __builtin_amdgcn_readfirstlane(ra.y);
            int s2 = __builtin_amdgcn_readfirstlane(ra.z);
            int s3 = __builtin_amdgcn_readfirstlane(ra.w);
            float4 p0 = zn[s0], p1 = zn[s1], p2 = zn[s2], p3 = zn[s3];
            float h0 = fmaxf(fmaf(p0.x, w1a, fmaf(p0.y, w1b, bb)), 0.0f) * p0.z;
            float h1 = fmaxf(fmaf(p1.x, w1a, fmaf(p1.y, w1b, bb)), 0.0f) * p1.z;
            float h2 = fmaxf(fmaf(p2.x, w1a, fmaf(p2.y, w1b, bb)), 0.0f) * p2.z;
            float h3 = fmaxf(fmaf(p3.x, w1a, fmaf(p3.y, w1b, bb)), 0.0f) * p3.z;
            acc += h0; acc += h1; acc += h2; acc += h3;
        }
        for (; j < n; ++j) {
            int s = __builtin_amdgcn_readfirstlane(row[j]);
            float4 p = zn[s];
            acc += fmaxf(fmaf(p.x, w1a, fmaf(p.y, w1b, bb)), 0.0f) * p.z;
        }
        A[w][l] = (float)acc * dv;         // wave-private row, no barrier needed
        double t = 0.0;
        #pragma unroll
        for (int jj = 0; jj < 64; ++jj)
            t += (double)A[w][jj] * (double)Wcs[jj * 64 + l];
        out[v * 64 + l] = rintf(fmaxf((float)t + bcl, 0.0f));
    }
}

// ---------------- launch ----------------

extern "C" void kernel_launch(void* const* d_in, const int* in_sizes, int n_in,
                              void* d_out, int out_size, void* d_ws, size_t ws_size,
                              hipStream_t stream) {
    const float* x    = (const float*)d_in[0];
    const int*   ei   = (const int*)  d_in[1];
    const float* W1   = (const float*)d_in[2];
    const float* b1   = (const float*)d_in[3];
    const float* W2   = (const float*)d_in[4];
    const float* b2   = (const float*)d_in[5];
    const float* Wfc  = (const float*)d_in[6];
    const float* bfc  = (const float*)d_in[7];
    float* out = (float*)d_out;

    const int* src = ei;
    const int* dst = ei + N_EDGES;

    // workspace layout (bytes), 16-aligned; total 70,420,736 (unchanged)
    // bins (14.68 MB) + bcnt alias the xdc/zn region [3,204,096 .. 19,204,096):
    // dead before k_post/k_l1a write xdc/zn (same-stream ordering).
    char* ws = (char*)d_ws;
    int*    cnt    = (int*)   (ws + 0);          //   800,000
    float4* xdc    = (float4*)(ws + 3204096);    // 3,200,000
    float4* zn     = (float4*)(ws + 6404096);    // 3,200,000
    int*    bins   = (int*)   (ws + 3204096);    // 14,680,064 (alias, dead after k_sort)
    int*    bcnt   = (int*)   (ws + 17884160);   //     2,048  (alias, dead after k_sort)
    int*    buf    = (int*)   (ws + 19204096);   // 51,200,000 padded adjacency
    float*  Wc     = (float*) (ws + 70404096);   //    16,384
    float*  bc     = (float*) (ws + 70420480);   //       256

    k_setup <<<NB_SCAN, 256, 0, stream>>>(W2, b2, Wfc, bfc, Wc, bc, bcnt);
    k_bin   <<<NB_BIN, 512, 0, stream>>>(src, dst, bins, bcnt);
    k_sort  <<<NFINE, 512, 0, stream>>>(bins, bcnt, cnt, buf);
    k_post  <<<NB_SCAN, 256, 0, stream>>>(cnt, (const float2*)x, xdc);
    k_l1a   <<<NB_SCAN, 256, 0, stream>>>(cnt, buf, xdc, zn);
    k_l2    <<<N_VAR / 16, 256, 0, stream>>>(cnt, buf, zn, W1, b1, Wc, bc, out);
}